// Round 1
// 306.722 us; speedup vs baseline: 1.3164x; 1.3164x over previous
//
#include <hip/hip_runtime.h>
#include <math.h>

// SSIM via fully separable pipeline, software-pipelined staging version.
// img1,img2: [32,3,512,512] fp32 -> scalar mean.
//
// ssim_kernel: one thread per image column; tile = 256 cols x 34 output rows.
//  - T14 async-STAGE split: global loads for rows r+2,r+3 are ISSUED into
//    registers right after the barrier, then ~2 rows of conv math run, then
//    the registers are COMMITTED to LDS. The vmcnt wait is covered by ~700
//    cycles of compute instead of stalling cold every row (old version had
//    prefetch distance 0: stage() loaded AND wrote LDS before compute).
//  - 2 rows per barrier (22 barriers vs 44), 4-row LDS ring buffer.
//  - ring phase r%11 stays compile-time: pair period 22 == 0 mod 11.
//  - 11-tap horizontal conv read directly from LDS (no register window).
//  - vertical conv in REGISTERS: 11-slot accumulator ring x 5 quantities,
//    scatter-FMA with compile-time ring indices; weight-index-0 tap assigns.
//  - per-thread ssim sum -> block reduce -> 1 float partial per block.
// reduce_kernel: single block sums 3072 partials in double, writes mean.
//
// Round-2 lesson: __launch_bounds__(256,4) (128-VGPR cap) forced the 55-reg
// ring into scratch (WRITE_SIZE 711 MB). Cap at 256 VGPRs instead.
// Round-3 theory: VALUBusy 58%, HBM 6.8% -> latency-bound on the per-row
// load->LDS chain, not issue-bound. This version attacks exactly that.

#define IH 512
#define IW 512
#define NCH 96            // 32*3 depthwise channels
#define TW 256            // tile width == blockDim.x
#define TH 34             // output rows per block
#define SSTR 272          // LDS row stride (266 used)
#define TYB 16            // ceil(512/34) block-rows
#define C1f (0.01f * 0.01f)
#define C2f (0.03f * 0.03f)

struct Weights { float w[11]; };

__global__ __launch_bounds__(256, 2) void ssim_kernel(
    const float* __restrict__ img1, const float* __restrict__ img2,
    float* __restrict__ partial, Weights wt)
{
    __shared__ float sA[4][SSTR];   // 4-row ring, buffer = row & 3
    __shared__ float sB[4][SSTR];
    __shared__ float wave_sums[4];

    const int tid = threadIdx.x;
    const int bx  = blockIdx.x;
    const int tx  = bx & 1;          // 2 col tiles
    const int ty  = (bx >> 1) & 15;  // 16 row tiles
    const int ch  = bx >> 5;         // 96 channels

    const int col0     = tx * TW;
    const int row_out0 = ty * TH;
    const int row0     = row_out0 - 5;       // staging row r -> global row row0+r
    const size_t choff = (size_t)ch * IH * IW;

    // column halo indices (fixed per thread)
    const int  gc0   = col0 - 5 + tid;
    const bool colv0 = ((unsigned)gc0 < (unsigned)IW);
    const int  gc1   = gc0 + TW;                   // staged by tid < 10
    const bool colv1 = ((unsigned)gc1 < (unsigned)IW);
    const bool halo  = (tid < 10);

    // two register staging slots (fixed names -> no runtime reg indexing)
    float pa0, pb0, pa1, pb1;        // slot P: even row of the pair
    float qa0, qb0, qa1, qb1;        // slot Q: odd row of the pair

    auto issue = [&](int r, float& a0, float& b0, float& a1, float& b1) {
        const int gr = row0 + r;                   // wave-uniform
        const bool rowv = ((unsigned)gr < (unsigned)IH);
        const long rowoff = (long)choff + (long)gr * IW;
        a0 = 0.f; b0 = 0.f; a1 = 0.f; b1 = 0.f;
        if (rowv & colv0) {
            a0 = img1[rowoff + gc0];
            b0 = img2[rowoff + gc0];
        }
        if (rowv & colv1 & halo) {
            a1 = img1[rowoff + gc1];
            b1 = img2[rowoff + gc1];
        }
    };
    auto commit = [&](int r, float a0, float b0, float a1, float b1) {
        const int p = r & 3;
        sA[p][tid] = a0;
        sB[p][tid] = b0;
        if (halo) {
            sA[p][tid + TW] = a1;
            sB[p][tid + TW] = b1;
        }
    };

    // accumulator ring: slot s holds output row o with o % 11 == s.
    // Zero-init only to avoid reading junk in the (discarded) warm-up emits.
    float acc0[11], acc1[11], acc2[11], acc3[11], acc4[11];
    #pragma unroll
    for (int s = 0; s < 11; ++s)
        acc0[s] = acc1[s] = acc2[s] = acc3[s] = acc4[s] = 0.f;

    float tsum = 0.f;

    // prologue: rows 0,1 staged (one-time full-latency wait)
    issue(0, pa0, pb0, pa1, pb1);
    issue(1, qa0, qb0, qa1, qb1);
    commit(0, pa0, pb0, pa1, pb1);
    commit(1, qa0, qb0, qa1, qb1);

    for (int g = 0; g < 2; ++g) {
        #pragma unroll
        for (int jj = 0; jj < 11; ++jj) {
            const int rp = g * 22 + jj * 2;   // this pair computes rows rp, rp+1
            __syncthreads();                  // prev commits visible; prev reads done

            const bool more = (rp + 2) < 44;  // wave-uniform
            if (more) {
                issue(rp + 2, pa0, pb0, pa1, pb1);
                issue(rp + 3, qa0, qb0, qa1, qb1);
            }

            #pragma unroll
            for (int e = 0; e < 2; ++e) {
                const int r  = rp + e;
                const int ph = (2 * jj + e) % 11;   // == r % 11, compile-time
                const int p  = r & 3;               // LDS ring buffer (runtime ok)

                // ---- horizontal 11-tap conv straight from LDS ----
                const float* __restrict__ rowA = &sA[p][tid];
                const float* __restrict__ rowB = &sB[p][tid];
                float hx = 0.f, hy = 0.f, hxx = 0.f, hyy = 0.f, hxy = 0.f;
                #pragma unroll
                for (int k = 0; k < 11; ++k) {
                    const float a  = rowA[k];
                    const float b  = rowB[k];
                    const float wk = wt.w[k];
                    const float ta = wk * a;
                    const float tb = wk * b;
                    hx  += ta;
                    hy  += tb;
                    hxx += ta * a;
                    hyy += tb * b;
                    hxy += ta * b;
                }

                // ---- vertical conv: scatter into ring, weight idx (ph-s) mod 11.
                //      wi==0 is the first tap of the slot's window -> assign. ----
                #pragma unroll
                for (int s = 0; s < 11; ++s) {
                    const int wi = (ph - s + 11) % 11;   // compile-time
                    const float wk = wt.w[wi];
                    if (wi == 0) {
                        acc0[s] = wk * hx;
                        acc1[s] = wk * hy;
                        acc2[s] = wk * hxx;
                        acc3[s] = wk * hyy;
                        acc4[s] = wk * hxy;
                    } else {
                        acc0[s] += wk * hx;
                        acc1[s] += wk * hy;
                        acc2[s] += wk * hxx;
                        acc3[s] += wk * hyy;
                        acc4[s] += wk * hxy;
                    }
                }

                // ---- emit output row o = r-10 (slot (ph+1)%11) ----
                const int se = (ph + 1) % 11;           // compile-time
                const float mu1 = acc0[se], mu2 = acc1[se];
                const float m11 = acc2[se], m22 = acc3[se], m12 = acc4[se];

                const float mu1s = mu1 * mu1;
                const float mu2s = mu2 * mu2;
                const float mu12 = mu1 * mu2;
                const float num = (2.f * mu12 + C1f) * (2.f * (m12 - mu12) + C2f);
                const float den = (mu1s + mu2s + C1f) *
                                  ((m11 - mu1s) + (m22 - mu2s) + C2f);
                const int o = r - 10;
                const bool valid = (o >= 0) && (row_out0 + o < IH);
                tsum += valid ? (num / den) : 0.f;
            }

            // ---- commit the prefetched pair: vmcnt wait covered by ~700cy of
            //      conv math above. Loads never cross the barrier. ----
            if (more) {
                commit(rp + 2, pa0, pb0, pa1, pb1);
                commit(rp + 3, qa0, qb0, qa1, qb1);
            }
        }
    }

    // ---- block reduction ----
    #pragma unroll
    for (int off = 32; off > 0; off >>= 1)
        tsum += __shfl_down(tsum, off);
    if ((tid & 63) == 0) wave_sums[tid >> 6] = tsum;
    __syncthreads();
    if (tid == 0) {
        partial[blockIdx.x] =
            wave_sums[0] + wave_sums[1] + wave_sums[2] + wave_sums[3];
    }
}

__global__ __launch_bounds__(256) void reduce_kernel(
    const float* __restrict__ partial, int n, float* __restrict__ out,
    double inv_count)
{
    __shared__ double wave_sums[4];
    const int tid = threadIdx.x;
    double s = 0.0;
    for (int i = tid; i < n; i += 256) s += (double)partial[i];
    #pragma unroll
    for (int off = 32; off > 0; off >>= 1)
        s += __shfl_down(s, off);
    if ((tid & 63) == 0) wave_sums[tid >> 6] = s;
    __syncthreads();
    if (tid == 0) {
        out[0] = (float)((wave_sums[0] + wave_sums[1] +
                          wave_sums[2] + wave_sums[3]) * inv_count);
    }
}

extern "C" void kernel_launch(void* const* d_in, const int* in_sizes, int n_in,
                              void* d_out, int out_size, void* d_ws, size_t ws_size,
                              hipStream_t stream)
{
    const float* img1 = (const float*)d_in[0];
    const float* img2 = (const float*)d_in[1];
    float* out = (float*)d_out;
    float* partial = (float*)d_ws;   // 3072 floats = 12 KB scratch

    // Gaussian window (ws=11, sigma=1.5) in fp32, matching the reference
    Weights wt;
    {
        float s = 0.f;
        for (int i = 0; i < 11; ++i) {
            const float d = (float)(i - 5);
            wt.w[i] = expf(-(d * d) / 4.5f);
            s += wt.w[i];
        }
        for (int i = 0; i < 11; ++i) wt.w[i] /= s;
    }

    const int nblocks = NCH * TYB * 2;   // 3072

    ssim_kernel<<<nblocks, 256, 0, stream>>>(img1, img2, partial, wt);

    const double inv_count = 1.0 / ((double)NCH * IH * IW);
    reduce_kernel<<<1, 256, 0, stream>>>(partial, nblocks, out, inv_count);
}